// Round 14
// baseline (121.863 us; speedup 1.0000x reference)
//
#include <hip/hip_runtime.h>

#define NB 4
#define CCH 256
#define NN 4096
#define DD 32

typedef __attribute__((ext_vector_type(8))) short bf16x8;
typedef __attribute__((ext_vector_type(8))) _Float16 f16x8;
typedef __attribute__((ext_vector_type(4))) _Float16 f16x4;
typedef __attribute__((ext_vector_type(2))) __fp16 fp16x2;
typedef __attribute__((ext_vector_type(4))) float f32x4;

#define MFB(a,b,c) __builtin_amdgcn_mfma_f32_16x16x32_bf16(a,b,c,0,0,0)
#define MFH(a,b,c) __builtin_amdgcn_mfma_f32_16x16x32_f16(a,b,c,0,0,0)
#define L2E 1.44269504f

__device__ inline unsigned short f2bf(float f){
    union { float f; unsigned u; } v; v.f = f;
    unsigned r = v.u + 0x7fffu + ((v.u >> 16) & 1u);
    return (unsigned short)(r >> 16);
}
__device__ inline float bfval(unsigned short h){
    union { unsigned u; float f; } v; v.u = ((unsigned)h) << 16; return v.f;
}
// native transcendental: D = 2^S0 (exactly what SL-folded softmax needs)
__device__ inline float vexp2(float x){
    float r; asm("v_exp_f32 %0, %1" : "=v"(r) : "v"(x)); return r;
}
__device__ inline f16x4 pk4(float p0, float p1, float p2, float p3){
    union { fp16x2 h2[2]; f16x4 v; } u;
    u.h2[0] = __builtin_amdgcn_cvt_pkrtz(p0, p1);
    u.h2[1] = __builtin_amdgcn_cvt_pkrtz(p2, p3);
    return u.v;
}

// ---------------------------------------------------------------- prep_w
// R27(b): convert weights to bf16 hi/lo ONCE. Previously every proj block
// re-converted w in-register (f2bf = ~4 VALU ops/value, duplicated 256x
// across blocks) -- ~80% of the proj kernels' VALU work, all redundant.
__global__ __launch_bounds__(256) void prep_w(
    const float* __restrict__ wq, const float* __restrict__ wk,
    const float* __restrict__ wv,
    unsigned short* __restrict__ wq_h, unsigned short* __restrict__ wq_l,
    unsigned short* __restrict__ wk_h, unsigned short* __restrict__ wk_l,
    unsigned short* __restrict__ wv_h, unsigned short* __restrict__ wv_l)
{
    const int idx = blockIdx.x*256 + threadIdx.x;   // 65536 threads
    if (idx < 8192) {
        float v = wq[idx];
        unsigned short h = f2bf(v);
        wq_h[idx] = h;
        wq_l[idx] = f2bf(v - bfval(h));
        v = wk[idx];
        h = f2bf(v);
        wk_h[idx] = h;
        wk_l[idx] = f2bf(v - bfval(h));
    }
    {
        float v = wv[idx];
        unsigned short h = f2bf(v);
        wv_h[idx] = h;
        wv_l[idx] = f2bf(v - bfval(h));
    }
}

// ---------------------------------------------------------------- proj_qk
// q output = SINGLE f16; k output = f16 hi/lo pair. Weights now PRELOADED
// as bf16 hi/lo fragments (16B loads) -- no in-loop w conversion.
__global__ __launch_bounds__(256) void proj_qk(
    const float* __restrict__ x,
    const unsigned short* __restrict__ wq_h, const unsigned short* __restrict__ wq_l,
    const float* __restrict__ bq,
    const unsigned short* __restrict__ wk_h, const unsigned short* __restrict__ wk_l,
    const float* __restrict__ bk,
    _Float16* __restrict__ q16,
    _Float16* __restrict__ k_hi, _Float16* __restrict__ k_lo)
{
    const int t = threadIdx.x;
    const int w = t >> 6;
    const int l = t & 63;
    const int lr = l & 15, lg = l >> 4;
    const int nb = blockIdx.x;
    const int b  = blockIdx.y;
    const int n0 = nb*64 + w*16;
    const int n  = n0 + lr;

    const float* xb = x + (size_t)b*CCH*NN;

    f32x4 acc[4] = {};

    for (int kc = 0; kc < 8; kc++) {
        const int cbase = kc*32 + lg*8;
        float xv[8];
        #pragma unroll
        for (int e = 0; e < 8; e++)
            xv[e] = xb[(size_t)(cbase + e)*NN + n];
        bf16x8 xh, xl;
        #pragma unroll
        for (int e = 0; e < 8; e++) {
            unsigned short h = f2bf(xv[e]);
            xh[e] = (short)h;
            xl[e] = (short)f2bf(xv[e] - bfval(h));
        }
        #pragma unroll
        for (int f = 0; f < 4; f++) {
            const size_t wo = (size_t)((f & 1)*16 + lr)*CCH + cbase;
            const unsigned short* wh_p = (f < 2) ? (wq_h + wo) : (wk_h + wo);
            const unsigned short* wl_p = (f < 2) ? (wq_l + wo) : (wk_l + wo);
            bf16x8 wh = *(const bf16x8*)wh_p;
            bf16x8 wl = *(const bf16x8*)wl_p;
            acc[f] = MFB(xh, wl, acc[f]);
            acc[f] = MFB(xl, wh, acc[f]);
            acc[f] = MFB(xh, wh, acc[f]);
        }
    }

    #pragma unroll
    for (int f = 0; f < 4; f++) {
        const int d = (f & 1)*16 + lr;
        const bool isq = (f < 2);
        float bias = isq ? bq[d] : bk[d];
        #pragma unroll
        for (int r = 0; r < 4; r++) {
            int nn = n0 + lg*4 + r;
            float val = acc[f][r] + bias;
            size_t a = ((size_t)(b*NN + nn))*DD + d;
            if (isq) {
                q16[a] = (_Float16)val;
            } else {
                _Float16 h = (_Float16)val;
                k_hi[a] = h;
                k_lo[a] = (_Float16)(val - (float)h);
            }
        }
    }
}

// ---------------------------------------------------------------- proj_v
// Output layout BLOCKED: v16[b][ib=n/8][c][8] (f16), 16B per (ib,c) chunk.
// Weights preloaded bf16 hi/lo (prep_w).
__global__ __launch_bounds__(512) void proj_v(
    const float* __restrict__ x,
    const unsigned short* __restrict__ wv_h, const unsigned short* __restrict__ wv_l,
    const float* __restrict__ bv,
    _Float16* __restrict__ v16)
{
    const int t = threadIdx.x;
    const int w = t >> 6;
    const int cg = w >> 2;
    const int ng = w & 3;
    const int l = t & 63;
    const int lr = l & 15, lg = l >> 4;
    const int ob = blockIdx.x;
    const int nb = blockIdx.y;
    const int b  = blockIdx.z;
    const int n0 = nb*64 + ng*16;
    const int n  = n0 + lr;
    const int cbase0 = ob*128 + cg*64;

    const float* xb = x + (size_t)b*CCH*NN;

    f32x4 acc[4] = {};

    for (int kc = 0; kc < 8; kc++) {
        const int kbase = kc*32 + lg*8;
        float xv[8];
        #pragma unroll
        for (int e = 0; e < 8; e++)
            xv[e] = xb[(size_t)(kbase + e)*NN + n];
        bf16x8 xh, xl;
        #pragma unroll
        for (int e = 0; e < 8; e++) {
            unsigned short h = f2bf(xv[e]);
            xh[e] = (short)h;
            xl[e] = (short)f2bf(xv[e] - bfval(h));
        }
        #pragma unroll
        for (int f = 0; f < 4; f++) {
            const size_t wo = (size_t)(cbase0 + f*16 + lr)*CCH + kbase;
            bf16x8 wh = *(const bf16x8*)(wv_h + wo);
            bf16x8 wl = *(const bf16x8*)(wv_l + wo);
            acc[f] = MFB(wl, xh, acc[f]);
            acc[f] = MFB(wh, xl, acc[f]);
            acc[f] = MFB(wh, xh, acc[f]);
        }
    }

    const size_t bslice = (size_t)b*(NN/8);
    #pragma unroll
    for (int f = 0; f < 4; f++) {
        #pragma unroll
        for (int r = 0; r < 4; r++) {
            int c = cbase0 + f*16 + lg*4 + r;
            float val = acc[f][r] + bv[c];
            v16[(((bslice + (n >> 3))*CCH + c) << 3) + (n & 7)] = (_Float16)val;
        }
    }
}

// ---------------------------------------------------------------- stats
// q single f16, k hi/lo f16 -> 2 MFMA per (f, j-step) instead of 3.
__global__ __launch_bounds__(512) void stats_kernel(
    const _Float16* __restrict__ q16,
    const _Float16* __restrict__ kh, const _Float16* __restrict__ kl,
    float* __restrict__ Zp)
{
    __shared__ float zW[8][64];
    const int t = threadIdx.x;
    const int w = t >> 6;
    const int l = t & 63;
    const int lr = l & 15, lg = l >> 4;
    const int it = blockIdx.x;   // 0..63 : i-tile
    const int jc = blockIdx.y;   // 0..1  : j-half (2048 j each)
    const int b  = blockIdx.z;
    const int ibase = it*64;
    const f32x4 zero = {0.f,0.f,0.f,0.f};

    f16x8 qf[4];
    #pragma unroll
    for (int f = 0; f < 4; f++) {
        size_t a = ((size_t)(b*NN + ibase + f*16 + lr))*DD + lg*8;
        qf[f] = *(const f16x8*)(q16 + a);
    }
    float Z[4] = {0.f, 0.f, 0.f, 0.f};

    const size_t k0 = ((size_t)(b*NN + jc*2048 + w*16 + lr))*DD + lg*8;
    const _Float16* kp  = kh + k0;
    const _Float16* klp = kl + k0;

    for (int jt = 0; jt < 16; ++jt) {
        f16x8 kh2 = *(const f16x8*)kp;
        f16x8 kl2 = *(const f16x8*)klp;
        #pragma unroll
        for (int f = 0; f < 4; f++) {
            f32x4 e = MFH(kl2, qf[f], zero);
            e = MFH(kh2, qf[f], e);
            Z[f] += vexp2(e[0]*L2E) + vexp2(e[1]*L2E)
                  + vexp2(e[2]*L2E) + vexp2(e[3]*L2E);
        }
        kp  += 128*DD;
        klp += 128*DD;
    }
    #pragma unroll
    for (int f = 0; f < 4; f++) {
        Z[f] += __shfl_xor(Z[f], 16, 64);
        Z[f] += __shfl_xor(Z[f], 32, 64);
        if (lg == 0) zW[w][f*16 + lr] = Z[f];
    }
    __syncthreads();
    if (t < 64) {
        float z = 0.f;
        #pragma unroll
        for (int w2 = 0; w2 < 8; ++w2) z += zW[w2][t];
        Zp[((size_t)jc*NB + b)*NN + ibase + t] = z;
    }
}

// ---------------------------------------------------------------- combine
__global__ __launch_bounds__(256) void combine_kernel(
    const float* __restrict__ Zp, float* __restrict__ Sx)
{
    const int idx = blockIdx.x*256 + threadIdx.x;   // b*NN + i, 16384 total
    Sx[idx] = log2f(Zp[idx] + Zp[(size_t)NB*NN + idx]);
}

// ---------------------------------------------------------------- attn
// R27(a) (from R26 evidence: full-rate K=32 PV verified -- MFMA busy
// 21.8us == 20.6us floor; wall 58.8 = chain exposure. R26 wrapped EACH
// jf's PV in setprio(1)/(0) -> 4 scheduler fences per step prevented
// QK(jf+1) from overlapping PV(jf) with only 2 waves/SIMD).
// Change: phase-split the step. Phase 1: all 4 jf QK+exp+pack (4
// independent MFMA->VALU chains = natural ILP). Phase 2: ONE un-fenced
// 32-MFH PV cluster, single setprio pair. pa[4] = +16 regs (peak ~250).
// Everything else identical to R26 (sigma-permuted q rows, K=32 PV).
__global__ __launch_bounds__(256, 2) void attn_kernel(
    const _Float16* __restrict__ q16,
    const _Float16* __restrict__ kh16, const _Float16* __restrict__ kl16,
    const _Float16* __restrict__ v16,
    const float* __restrict__ Sx,
    const float* __restrict__ x, const float* __restrict__ gamma,
    float* __restrict__ out)
{
    __shared__ __align__(16) f32x4 Rb[4096];   // 64KB end-reduce buffer

    const int t = threadIdx.x;
    const int wv = t >> 6;       // i-quarter 0..3
    const int l = t & 63;
    const int lr = l & 15, lg = l >> 4;

    // XCD slice: lin&7 = (b,ct) -> one slice per XCD (~1.8MB, L2-resident).
    const int lin = blockIdx.x;
    const int slice = lin & 7;
    const int b   = slice >> 1;
    const int ct  = slice & 1;
    const int jt  = lin >> 3;    // 0..63
    const int jbase = jt*64, cbase = ct*128;

    // K B-fragments: 4 j-frags, f16 hi/lo (persistent; 32 VGPR)
    f16x8 kfh[4], kfl[4];
    #pragma unroll
    for (int jf = 0; jf < 4; jf++) {
        size_t a = ((size_t)(b*NN + jbase + jf*16 + lr))*DD + lg*8;
        kfh[jf] = *(const f16x8*)(kh16 + a);
        kfl[jf] = *(const f16x8*)(kl16 + a);
    }

    const float* Sb = Sx + (size_t)b*NN;
    const _Float16* vb = v16 + (size_t)b*(NN/8)*CCH*8;

    const int i0 = wv*1024;     // this wave's i-quarter; 32 steps of 32

    // sigma-permuted q pointers: step A rows 8(lr>>2)+(lr&3), step B +4
    const int sigma = 8*(lr >> 2) + (lr & 3);
    const _Float16* qpA = q16 + ((size_t)(b*NN + i0 + sigma))*DD + lg*8;
    const _Float16* qpB = qpA + 4*DD;
    // s pointers follow sigma: lane lg covers i = 8lg+r (A), 8lg+4+r (B)
    const float* spA = Sb + i0 + 8*lg;
    const float* spB = spA + 4;
    // V B-frag: lane (lr,lg) reads 16B block ib = i0/8 + lg, c = ..+lr
    const _Float16* vp = vb + (((size_t)(i0/8 + lg)*CCH + cbase + lr) << 3);

    f32x4 acc[4][8] = {};   // [jf][cf] -- ONLY static subscripts below!

    #pragma clang loop unroll(disable)
    for (int s = 0; s < 32; ++s) {
        // loads for THIS step (L2-resident; TLP hides the latency)
        f16x8 qA = *(const f16x8*)qpA;  qpA += 32*DD;
        f16x8 qB = *(const f16x8*)qpB;  qpB += 32*DD;
        float4 sA4 = *(const float4*)spA; spA += 32;
        float4 sB4 = *(const float4*)spB; spB += 32;
        f16x8 vv[8];
        #pragma unroll
        for (int cf = 0; cf < 8; cf++)
            vv[cf] = *(const f16x8*)(vp + cf*128);
        vp += 32*CCH;

        // ---- Phase 1: all 4 jf QK + exp + pack (independent chains) ----
        f16x8 pa[4];
        #pragma unroll
        for (int jf = 0; jf < 4; jf++) {
            f32x4 eA = {};
            eA = MFH(qA, kfl[jf], eA);
            eA = MFH(qA, kfh[jf], eA);
            f32x4 eB = {};
            eB = MFH(qB, kfl[jf], eB);
            eB = MFH(qB, kfh[jf], eB);
            union { f16x4 h4[2]; f16x8 h8; } pu;
            pu.h4[0] = pk4(vexp2(fmaf(eA[0], L2E, -sA4.x)),
                           vexp2(fmaf(eA[1], L2E, -sA4.y)),
                           vexp2(fmaf(eA[2], L2E, -sA4.z)),
                           vexp2(fmaf(eA[3], L2E, -sA4.w)));
            pu.h4[1] = pk4(vexp2(fmaf(eB[0], L2E, -sB4.x)),
                           vexp2(fmaf(eB[1], L2E, -sB4.y)),
                           vexp2(fmaf(eB[2], L2E, -sB4.z)),
                           vexp2(fmaf(eB[3], L2E, -sB4.w)));
            pa[jf] = pu.h8;
        }

        // ---- Phase 2: ONE un-fenced PV cluster (32 full-rate MFH) ----
        __builtin_amdgcn_s_setprio(1);
        #pragma unroll
        for (int jf = 0; jf < 4; jf++)
            #pragma unroll
            for (int cf = 0; cf < 8; cf++)
                acc[jf][cf] = MFH(pa[jf], vv[cf], acc[jf][cf]);
        __builtin_amdgcn_s_setprio(0);
    }

    // ------------- 3-barrier tree reduce over the 4 i-quarters -------------
    // All acc subscripts literal. slot(jf,cf) = (jf*8+cf)<<6 | lane.
    if (wv == 2) {
        #pragma unroll
        for (int jf = 0; jf < 4; jf++)
            #pragma unroll
            for (int cf = 0; cf < 8; cf++)
                Rb[((jf*8 + cf) << 6) + l] = acc[jf][cf];
    } else if (wv == 3) {
        #pragma unroll
        for (int jf = 0; jf < 4; jf++)
            #pragma unroll
            for (int cf = 0; cf < 8; cf++)
                Rb[2048 + ((jf*8 + cf) << 6) + l] = acc[jf][cf];
    }
    __syncthreads();
    if (wv == 0) {
        #pragma unroll
        for (int jf = 0; jf < 4; jf++)
            #pragma unroll
            for (int cf = 0; cf < 8; cf++)
                acc[jf][cf] += Rb[((jf*8 + cf) << 6) + l];
    } else if (wv == 1) {
        #pragma unroll
        for (int jf = 0; jf < 4; jf++)
            #pragma unroll
            for (int cf = 0; cf < 8; cf++)
                acc[jf][cf] += Rb[2048 + ((jf*8 + cf) << 6) + l];
    }
    __syncthreads();
    if (wv == 0) {          // gives jf {2,3} at base 0, slots {0,1}
        #pragma unroll
        for (int cf = 0; cf < 8; cf++) {
            Rb[((0*8 + cf) << 6) + l] = acc[2][cf];
            Rb[((1*8 + cf) << 6) + l] = acc[3][cf];
        }
    } else if (wv == 1) {   // gives jf {0,1} at base 2048, slots {0,1}
        #pragma unroll
        for (int cf = 0; cf < 8; cf++) {
            Rb[2048 + ((0*8 + cf) << 6) + l] = acc[0][cf];
            Rb[2048 + ((1*8 + cf) << 6) + l] = acc[1][cf];
        }
    }
    __syncthreads();

    const float gam = gamma[0];
    // Final: wv0 outputs jf {0,1} (reads wave1's halves at base 2048);
    //        wv1 outputs jf {2,3} (reads wave0's halves at base 0).
    if (wv == 0) {
        #pragma unroll
        for (int cf = 0; cf < 8; cf++) {
            {   // jf = 0 (wave1 stored at base 2048, slot 0)
                f32x4 o = Rb[2048 + ((0*8 + cf) << 6) + l];
                f32x4 a = acc[0][cf];
                a[0]+=o[0]; a[1]+=o[1]; a[2]+=o[2]; a[3]+=o[3];
                const int c = cbase + cf*16 + lr;
                const int j = jbase + 0*16 + lg*4;
                size_t off = ((size_t)(b*CCH + c))*NN + j;
                float4 xv = *(const float4*)(x + off);
                float4 ov;
                ov.x = fmaf(gam, a[0], xv.x);
                ov.y = fmaf(gam, a[1], xv.y);
                ov.z = fmaf(gam, a[2], xv.z);
                ov.w = fmaf(gam, a[3], xv.w);
                *(float4*)(out + off) = ov;
            }
            {   // jf = 1 (base 2048, slot 1)
                f32x4 o = Rb[2048 + ((1*8 + cf) << 6) + l];
                f32x4 a = acc[1][cf];
                a[0]+=o[0]; a[1]+=o[1]; a[2]+=o[2]; a[3]+=o[3];
                const int c = cbase + cf*16 + lr;
                const int j = jbase + 1*16 + lg*4;
                size_t off = ((size_t)(b*CCH + c))*NN + j;
                float4 xv = *(const float4*)(x + off);
                float4 ov;
                ov.x = fmaf(gam, a[0], xv.x);
                ov.y = fmaf(gam, a[1], xv.y);
                ov.z = fmaf(gam, a[2], xv.z);
                ov.w = fmaf(gam, a[3], xv.w);
                *(float4*)(out + off) = ov;
            }
        }
    } else if (wv == 1) {
        #pragma unroll
        for (int cf = 0; cf < 8; cf++) {
            {   // jf = 2 (wave0 stored at base 0, slot 0)
                f32x4 o = Rb[((0*8 + cf) << 6) + l];
                f32x4 a = acc[2][cf];
                a[0]+=o[0]; a[1]+=o[1]; a[2]+=o[2]; a[3]+=o[3];
                const int c = cbase + cf*16 + lr;
                const int j = jbase + 2*16 + lg*4;
                size_t off = ((size_t)(b*CCH + c))*NN + j;
                float4 xv = *(const float4*)(x + off);
                float4 ov;
                ov.x = fmaf(gam, a[0], xv.x);
                ov.y = fmaf(gam, a[1], xv.y);
                ov.z = fmaf(gam, a[2], xv.z);
                ov.w = fmaf(gam, a[3], xv.w);
                *(float4*)(out + off) = ov;
            }
            {   // jf = 3 (base 0, slot 1)
                f32x4 o = Rb[((1*8 + cf) << 6) + l];
                f32x4 a = acc[3][cf];
                a[0]+=o[0]; a[1]+=o[1]; a[2]+=o[2]; a[3]+=o[3];
                const int c = cbase + cf*16 + lr;
                const int j = jbase + 3*16 + lg*4;
                size_t off = ((size_t)(b*CCH + c))*NN + j;
                float4 xv = *(const float4*)(x + off);
                float4 ov;
                ov.x = fmaf(gam, a[0], xv.x);
                ov.y = fmaf(gam, a[1], xv.y);
                ov.z = fmaf(gam, a[2], xv.z);
                ov.w = fmaf(gam, a[3], xv.w);
                *(float4*)(out + off) = ov;
            }
        }
    }
}

// ---------------------------------------------------------------- launch
extern "C" void kernel_launch(void* const* d_in, const int* in_sizes, int n_in,
                              void* d_out, int out_size, void* d_ws, size_t ws_size,
                              hipStream_t stream)
{
    (void)in_sizes; (void)n_in; (void)out_size; (void)ws_size;
    const float* x     = (const float*)d_in[0];
    const float* wq    = (const float*)d_in[1];
    const float* bq    = (const float*)d_in[2];
    const float* wk    = (const float*)d_in[3];
    const float* bk    = (const float*)d_in[4];
    const float* wv    = (const float*)d_in[5];
    const float* bv    = (const float*)d_in[6];
    const float* gamma = (const float*)d_in[7];
    float* out = (float*)d_out;

    char* ws = (char*)d_ws;
    _Float16* q16  = (_Float16*)(ws + 0x000000);  // 1MB (f16 single)
    _Float16* k_hi = (_Float16*)(ws + 0x100000);  // 1MB (f16 hi)
    _Float16* k_lo = (_Float16*)(ws + 0x200000);  // 1MB (f16 lo)
    _Float16* v16  = (_Float16*)(ws + 0x400000);  // 8MB blocked
    float*    Zp   = (float*)   (ws + 0xC00000);  // 128KB partials
    float*    Sx   = (float*)   (ws + 0xC20000);  // 64KB (SL)
    unsigned short* wq_h = (unsigned short*)(ws + 0xC30000);  // 16KB
    unsigned short* wq_l = (unsigned short*)(ws + 0xC34000);  // 16KB
    unsigned short* wk_h = (unsigned short*)(ws + 0xC38000);  // 16KB
    unsigned short* wk_l = (unsigned short*)(ws + 0xC3C000);  // 16KB
    unsigned short* wv_h = (unsigned short*)(ws + 0xC40000);  // 128KB
    unsigned short* wv_l = (unsigned short*)(ws + 0xC60000);  // 128KB

    prep_w<<<dim3(256),       256, 0, stream>>>(wq, wk, wv,
                                                wq_h, wq_l, wk_h, wk_l,
                                                wv_h, wv_l);
    proj_qk<<<dim3(64, 4),    256, 0, stream>>>(x, wq_h, wq_l, bq,
                                                wk_h, wk_l, bk,
                                                q16, k_hi, k_lo);
    proj_v <<<dim3(2, 64, 4), 512, 0, stream>>>(x, wv_h, wv_l, bv, v16);
    stats_kernel  <<<dim3(64, 2, 4), 512, 0, stream>>>(q16, k_hi, k_lo, Zp);
    combine_kernel<<<dim3(64),       256, 0, stream>>>(Zp, Sx);
    attn_kernel   <<<dim3(512),      256, 0, stream>>>(
        q16, k_hi, k_lo, v16, Sx, x, gamma, out);
}